// Round 1
// baseline (206.826 us; speedup 1.0000x reference)
//
#include <hip/hip_runtime.h>

// Sizes fixed by the problem.
#define BS    64
#define KDIM  256   // in_dim
#define ICAP  256   // I = 16*16
#define JCAP  64    // J out-caps
#define D2    32
#define OUTD  2048  // J*D2

typedef short bf16x8 __attribute__((ext_vector_type(8)));
typedef float f32x4  __attribute__((ext_vector_type(4)));

static __device__ __forceinline__ float bf2f(unsigned u16) {
  union { unsigned u; float f; } v; v.u = u16 << 16; return v.f;
}
static __device__ __forceinline__ unsigned short f2bf(float x) {
  union { float f; unsigned u; } v; v.f = x;
  unsigned r = v.u + 0x7fffu + ((v.u >> 16) & 1u);
  return (unsigned short)(r >> 16);
}
static __device__ __forceinline__ void unpack8(uint4 u, float* f) {
  f[0] = bf2f(u.x & 0xffffu); f[1] = bf2f(u.x >> 16);
  f[2] = bf2f(u.y & 0xffffu); f[3] = bf2f(u.y >> 16);
  f[4] = bf2f(u.z & 0xffffu); f[5] = bf2f(u.z >> 16);
  f[6] = bf2f(u.w & 0xffffu); f[7] = bf2f(u.w >> 16);
}

// ---------------------------------------------------------------------------
// prep:
//   [0,256)      conv_w   : W f32 -> Wbf bf16            [OUTD][KDIM]
//   [256,1280)   x-tiles  : x f32 -> xT bf16 [b][i][k] AND xKI bf16 [b][k][i]
//   [1280,1536)  softmax  : c0[b][j][i] = softmax_j(b_init) bf16, + cpart
// ---------------------------------------------------------------------------
__global__ __launch_bounds__(256) void prep(
    const float* __restrict__ W, const float* __restrict__ x,
    const float* __restrict__ Binit,
    unsigned short* __restrict__ Wbf, unsigned short* __restrict__ xT,
    unsigned short* __restrict__ xKI, unsigned short* __restrict__ c0,
    float* __restrict__ cpart)           // [BS][4][JCAP] csum partials
{
  __shared__ union {
    float Ls[64][65];   // transpose tile
    struct { float Bs[64][68]; float mx[64]; float inv[64]; } S;
  } sm;
  const int t   = threadIdx.x;
  const int blk = blockIdx.x;

  if (blk < 256) {
    // ---- conv_w ----
    const int g = blk * 256 + t;
    const float* s = W + (size_t)g * 8;
    f32x4 a = *(const f32x4*)s;
    f32x4 b = *(const f32x4*)(s + 4);
    uint4 o;
    o.x = (unsigned)f2bf(a.x) | ((unsigned)f2bf(a.y) << 16);
    o.y = (unsigned)f2bf(a.z) | ((unsigned)f2bf(a.w) << 16);
    o.z = (unsigned)f2bf(b.x) | ((unsigned)f2bf(b.y) << 16);
    o.w = (unsigned)f2bf(b.z) | ((unsigned)f2bf(b.w) << 16);
    *(uint4*)(Wbf + (size_t)g * 8) = o;
  } else if (blk < 1280) {
    // ---- x tile: load f32 [k][i] tile, emit xT (transposed) + xKI (cast) ----
    const int bid = blk - 256;
    const int i0  = (bid & 3) * 64;
    const int k0  = ((bid >> 2) & 3) * 64;
    const int b   = bid >> 4;
    for (int it = 0; it < 4; ++it) {
      const int k  = it * 16 + (t >> 4);
      const int i4 = (t & 15) * 4;
      f32x4 v = *(const f32x4*)(x + ((size_t)(b * KDIM + k0 + k) * ICAP) + i0 + i4);
      sm.Ls[k][i4 + 0] = v.x; sm.Ls[k][i4 + 1] = v.y;
      sm.Ls[k][i4 + 2] = v.z; sm.Ls[k][i4 + 3] = v.w;
    }
    __syncthreads();
    {   // xT[b][i][k] (transposed)
      const int i  = t >> 2;
      const int kc = (t & 3) * 16;
      unsigned pk[8];
      for (int q = 0; q < 8; ++q) {
        float lo = sm.Ls[kc + 2 * q][i];
        float hi = sm.Ls[kc + 2 * q + 1][i];
        pk[q] = (unsigned)f2bf(lo) | ((unsigned)f2bf(hi) << 16);
      }
      unsigned short* dst = xT + ((size_t)(b * ICAP + i0 + i) * KDIM) + k0 + kc;
      uint4 s0; s0.x = pk[0]; s0.y = pk[1]; s0.z = pk[2]; s0.w = pk[3];
      uint4 s1; s1.x = pk[4]; s1.y = pk[5]; s1.z = pk[6]; s1.w = pk[7];
      *(uint4*)dst       = s0;
      *(uint4*)(dst + 8) = s1;
    }
    {   // xKI[b][k][i] (straight bf16 cast)
      const int k   = t >> 2;
      const int ic4 = (t & 3) * 16;
      unsigned pk[8];
      for (int h = 0; h < 8; ++h) {
        float lo = sm.Ls[k][ic4 + 2 * h];
        float hi = sm.Ls[k][ic4 + 2 * h + 1];
        pk[h] = (unsigned)f2bf(lo) | ((unsigned)f2bf(hi) << 16);
      }
      unsigned short* dst = xKI + ((size_t)(b * KDIM + k0 + k) * ICAP) + i0 + ic4;
      uint4 s0; s0.x = pk[0]; s0.y = pk[1]; s0.z = pk[2]; s0.w = pk[3];
      uint4 s1; s1.x = pk[4]; s1.y = pk[5]; s1.z = pk[6]; s1.w = pk[7];
      *(uint4*)dst       = s0;
      *(uint4*)(dst + 8) = s1;
    }
  } else {
    // ---- softmax_c0 -> c0[b][j][i] bf16 + cpart[b][q][j] ----
    const int bid = blk - 1280;
    const int b   = bid >> 2;
    const int q   = bid & 3;
    {
      const int j  = t >> 2;
      const int c4 = (t & 3) * 16;
      const float* src = Binit + ((size_t)(b * JCAP + j) * ICAP) + q * 64 + c4;
      for (int r = 0; r < 4; ++r)
        *(f32x4*)&sm.S.Bs[j][c4 + r * 4] = *(const f32x4*)(src + r * 4);
    }
    __syncthreads();
    if (t < 64) {
      const int ii = t;
      float m = -3.0e38f;
      for (int j = 0; j < 64; ++j) m = fmaxf(m, sm.S.Bs[j][ii]);
      float se = 0.f;
      for (int j = 0; j < 64; ++j) se += __expf(sm.S.Bs[j][ii] - m);
      sm.S.mx[ii]  = m;
      sm.S.inv[ii] = 1.0f / se;
    }
    __syncthreads();
    {
      const int j  = t >> 2;
      const int c4 = (t & 3) * 16;
      float cs = 0.f;
      unsigned pk[8];
      for (int h = 0; h < 8; ++h) {
        const int i0 = c4 + 2 * h;
        float lo = __expf(sm.S.Bs[j][i0]     - sm.S.mx[i0])     * sm.S.inv[i0];
        float hi = __expf(sm.S.Bs[j][i0 + 1] - sm.S.mx[i0 + 1]) * sm.S.inv[i0 + 1];
        cs += lo + hi;
        pk[h] = (unsigned)f2bf(lo) | ((unsigned)f2bf(hi) << 16);
      }
      unsigned short* dst = c0 + ((size_t)(b * JCAP + j) * ICAP) + q * 64 + c4;
      uint4 s0; s0.x = pk[0]; s0.y = pk[1]; s0.z = pk[2]; s0.w = pk[3];
      uint4 s1; s1.x = pk[4]; s1.y = pk[5]; s1.z = pk[6]; s1.w = pk[7];
      *(uint4*)dst       = s0;
      *(uint4*)(dst + 8) = s1;
      cs += __shfl_xor(cs, 1, 64);
      cs += __shfl_xor(cs, 2, 64);
      if ((t & 3) == 0) cpart[((size_t)(b * 4 + q)) * JCAP + j] = cs;
    }
  }
}

// ---------------------------------------------------------------------------
// k_sv: Y^T[k][j] = sum_i xKI[b][k][i]*c[b][j][i]  (MFMA, m=k, n=j, kdim=i),
// then spart[b][kc][j*32+d] = sum_{k in slice} Wbf[j*32+d][k]*Y[k][j].
// grid 256 = (b, kc); bias (csum*Wb) added by the consumer.
// ---------------------------------------------------------------------------
__global__ __launch_bounds__(256) void k_sv(
    const unsigned short* __restrict__ xKI,   // [BS][KDIM][ICAP] bf16
    const unsigned short* __restrict__ cmat,  // [BS][JCAP][ICAP] bf16
    const unsigned short* __restrict__ Wbf,   // [OUTD][KDIM] bf16
    float* __restrict__ spart)                // [BS][4][OUTD] f32
{
  __shared__ float Y[64][68];
  const int tid = threadIdx.x;
  const int b   = blockIdx.x >> 2;
  const int kc  = blockIdx.x & 3;
  const int l   = tid & 63;
  const int w   = tid >> 6;

  f32x4 acc[4];
  for (int n = 0; n < 4; ++n) acc[n] = (f32x4){0.f, 0.f, 0.f, 0.f};

  const unsigned short* Ap =
      xKI + ((size_t)(b * KDIM + kc * 64 + w * 16 + (l & 15))) * ICAP + (l >> 4) * 8;
  const unsigned short* Bp =
      cmat + ((size_t)(b * JCAP + (l & 15))) * ICAP + (l >> 4) * 8;
#pragma unroll
  for (int ks = 0; ks < 8; ++ks) {
    bf16x8 a = *(const bf16x8*)(Ap + ks * 32);
#pragma unroll
    for (int n = 0; n < 4; ++n) {
      bf16x8 bb = *(const bf16x8*)(Bp + (size_t)n * 16 * ICAP + ks * 32);
      acc[n] = __builtin_amdgcn_mfma_f32_16x16x32_bf16(a, bb, acc[n], 0, 0, 0);
    }
  }
#pragma unroll
  for (int n = 0; n < 4; ++n)
#pragma unroll
    for (int r = 0; r < 4; ++r)
      Y[w * 16 + (l >> 4) * 4 + r][n * 16 + (l & 15)] = acc[n][r];
  __syncthreads();

  const int j = tid >> 2;
  float sacc[8];
#pragma unroll
  for (int d = 0; d < 8; ++d) sacc[d] = 0.f;
  const unsigned short* wbase = Wbf + (size_t)(tid * 8) * KDIM + kc * 64;
  for (int k8 = 0; k8 < 8; ++k8) {
    float y8[8];
#pragma unroll
    for (int e = 0; e < 8; ++e) y8[e] = Y[k8 * 8 + e][j];
#pragma unroll
    for (int d = 0; d < 8; ++d) {
      uint4 u = *(const uint4*)(wbase + (size_t)d * KDIM + k8 * 8);
      float f[8]; unpack8(u, f);
      float s = sacc[d];
#pragma unroll
      for (int e = 0; e < 8; ++e) s += f[e] * y8[e];
      sacc[d] = s;
    }
  }
  float* dst = spart + ((size_t)(b * 4 + kc)) * OUTD + tid * 8;
  f32x4 t0 = {sacc[0], sacc[1], sacc[2], sacc[3]};
  f32x4 t1 = {sacc[4], sacc[5], sacc[6], sacc[7]};
  *(f32x4*)dst       = t0;
  *(f32x4*)(dst + 4) = t1;
}

// ---------------------------------------------------------------------------
// k_u: v = squash(sum_kc spart + csum*Wb) (redundant per block), then
// U[j][k] = sum_d v[j][d]*W[j*32+d][k], stored as bf16 hi+lo pair.
// grid 256 = (b, kc).
// ---------------------------------------------------------------------------
__global__ __launch_bounds__(256) void k_u(
    const float* __restrict__ spart, const float* __restrict__ cpart,
    const float* __restrict__ Wb, const unsigned short* __restrict__ Wbf,
    unsigned short* __restrict__ Uhi, unsigned short* __restrict__ Ulo)
{
  __shared__ float vls[JCAP * 33];
  const int tid = threadIdx.x;
  const int b   = blockIdx.x >> 2;
  const int kc  = blockIdx.x & 3;
  const int j   = tid >> 2;
  {
    const float* sp = spart + (size_t)b * 4 * OUTD + tid * 8;
    f32x4 a0 = *(const f32x4*)sp;
    f32x4 a1 = *(const f32x4*)(sp + 4);
    for (int p = 1; p < 4; ++p) {
      a0 += *(const f32x4*)(sp + (size_t)p * OUTD);
      a1 += *(const f32x4*)(sp + (size_t)p * OUTD + 4);
    }
    float cs = cpart[((size_t)b * 4) * JCAP + j] + cpart[((size_t)(b * 4 + 1)) * JCAP + j] +
               cpart[((size_t)(b * 4 + 2)) * JCAP + j] + cpart[((size_t)(b * 4 + 3)) * JCAP + j];
    f32x4 wb0 = *(const f32x4*)(Wb + tid * 8);
    f32x4 wb1 = *(const f32x4*)(Wb + tid * 8 + 4);
    float s8[8];
    s8[0] = a0.x + cs * wb0.x; s8[1] = a0.y + cs * wb0.y;
    s8[2] = a0.z + cs * wb0.z; s8[3] = a0.w + cs * wb0.w;
    s8[4] = a1.x + cs * wb1.x; s8[5] = a1.y + cs * wb1.y;
    s8[6] = a1.z + cs * wb1.z; s8[7] = a1.w + cs * wb1.w;
    float sq = 0.f;
    for (int e = 0; e < 8; ++e) sq += s8[e] * s8[e];
    sq += __shfl_xor(sq, 1, 64);
    sq += __shfl_xor(sq, 2, 64);
    float scale = (sq / (1.0f + sq)) / sqrtf(sq + 1e-8f);
    const int d0 = (tid & 3) * 8;
    for (int e = 0; e < 8; ++e) vls[j * 33 + d0 + e] = scale * s8[e];
  }
  __syncthreads();

  const int kg = kc * 64 + (tid & 3) * 16;
  float acc[16];
#pragma unroll
  for (int e = 0; e < 16; ++e) acc[e] = 0.f;
  const float* vj = vls + j * 33;
  const unsigned short* wrow = Wbf + (size_t)(j * D2) * KDIM + kg;
  for (int d = 0; d < 32; ++d) {
    float vd = vj[d];
    uint4 u0 = *(const uint4*)(wrow + (size_t)d * KDIM);
    uint4 u1 = *(const uint4*)(wrow + (size_t)d * KDIM + 8);
    float f[16]; unpack8(u0, f); unpack8(u1, f + 8);
#pragma unroll
    for (int e = 0; e < 16; ++e) acc[e] += vd * f[e];
  }
  unsigned ph[8], pl[8];
  for (int h = 0; h < 8; ++h) {
    unsigned short h0 = f2bf(acc[2 * h]), h1 = f2bf(acc[2 * h + 1]);
    float r0 = acc[2 * h] - bf2f(h0), r1 = acc[2 * h + 1] - bf2f(h1);
    ph[h] = (unsigned)h0 | ((unsigned)h1 << 16);
    pl[h] = (unsigned)f2bf(r0) | ((unsigned)f2bf(r1) << 16);
  }
  size_t off = ((size_t)(b * JCAP + j)) * KDIM + kg;
  uint4 q0; q0.x = ph[0]; q0.y = ph[1]; q0.z = ph[2]; q0.w = ph[3];
  uint4 q1; q1.x = ph[4]; q1.y = ph[5]; q1.z = ph[6]; q1.w = ph[7];
  *(uint4*)(Uhi + off)     = q0;
  *(uint4*)(Uhi + off + 8) = q1;
  uint4 q2; q2.x = pl[0]; q2.y = pl[1]; q2.z = pl[2]; q2.w = pl[3];
  uint4 q3; q3.x = pl[4]; q3.y = pl[5]; q3.z = pl[6]; q3.w = pl[7];
  *(uint4*)(Ulo + off)     = q2;
  *(uint4*)(Ulo + off + 8) = q3;
}

// ---------------------------------------------------------------------------
// k_db: db[i][j] = sum_k xT[b][i][k]*U[j][k] (MFMA, hi+lo), bnew = bold+db+ub,
// softmax over j -> c bf16 [b][j][i] + csum partials; blog written on pass 1.
// grid 256 = (b, ic); block covers i in [ic*64, ic*64+64).
// ---------------------------------------------------------------------------
__global__ __launch_bounds__(256) void k_db(
    const unsigned short* __restrict__ xT,    // [BS][ICAP][KDIM] bf16
    const unsigned short* __restrict__ Uhi, const unsigned short* __restrict__ Ulo,
    const float* __restrict__ spart, const float* __restrict__ cpart_in,
    const float* __restrict__ Wb,
    const float* __restrict__ Binit,          // [BS][JCAP][ICAP] f32 (pass 1)
    float* __restrict__ blog,                 // [BS][ICAP][JCAP] f32
    unsigned short* __restrict__ cmat,        // out c bf16 [BS][JCAP][ICAP]
    float* __restrict__ cpart_out,
    const int pass)
{
  __shared__ struct {
    float dbl[64][68];
    float ub[64];
    unsigned short ct[64][66];
    float cpw[4][66];
  } sm;
  const int tid = threadIdx.x;
  const int b   = blockIdx.x >> 2;
  const int ic  = blockIdx.x & 3;
  const int i0  = ic * 64;
  const int l   = tid & 63;
  const int w   = tid >> 6;

  // ---- phase0: ubias[j] = sum_d v[j][d]*Wb[j*32+d] (redundant v recompute) ----
  {
    const float* sp = spart + (size_t)b * 4 * OUTD + tid * 8;
    f32x4 a0 = *(const f32x4*)sp;
    f32x4 a1 = *(const f32x4*)(sp + 4);
    for (int p = 1; p < 4; ++p) {
      a0 += *(const f32x4*)(sp + (size_t)p * OUTD);
      a1 += *(const f32x4*)(sp + (size_t)p * OUTD + 4);
    }
    const int j = tid >> 2;
    float cs = cpart_in[((size_t)b * 4) * JCAP + j] + cpart_in[((size_t)(b * 4 + 1)) * JCAP + j] +
               cpart_in[((size_t)(b * 4 + 2)) * JCAP + j] + cpart_in[((size_t)(b * 4 + 3)) * JCAP + j];
    f32x4 wb0 = *(const f32x4*)(Wb + tid * 8);
    f32x4 wb1 = *(const f32x4*)(Wb + tid * 8 + 4);
    float s8[8];
    s8[0] = a0.x + cs * wb0.x; s8[1] = a0.y + cs * wb0.y;
    s8[2] = a0.z + cs * wb0.z; s8[3] = a0.w + cs * wb0.w;
    s8[4] = a1.x + cs * wb1.x; s8[5] = a1.y + cs * wb1.y;
    s8[6] = a1.z + cs * wb1.z; s8[7] = a1.w + cs * wb1.w;
    float sq = 0.f;
    for (int e = 0; e < 8; ++e) sq += s8[e] * s8[e];
    sq += __shfl_xor(sq, 1, 64);
    sq += __shfl_xor(sq, 2, 64);
    float scale = (sq / (1.0f + sq)) / sqrtf(sq + 1e-8f);
    float ub = scale * (s8[0] * wb0.x + s8[1] * wb0.y + s8[2] * wb0.z + s8[3] * wb0.w +
                        s8[4] * wb1.x + s8[5] * wb1.y + s8[6] * wb1.z + s8[7] * wb1.w);
    ub += __shfl_xor(ub, 1, 64);
    ub += __shfl_xor(ub, 2, 64);
    if ((tid & 3) == 0) sm.ub[j] = ub;
  }

  // ---- db GEMM: A = xT rows i, B = Uhi/Ulo rows j ----
  f32x4 acc[4];
  for (int n = 0; n < 4; ++n) acc[n] = (f32x4){0.f, 0.f, 0.f, 0.f};
  const unsigned short* Ap =
      xT + ((size_t)(b * ICAP + i0 + w * 16 + (l & 15))) * KDIM + (l >> 4) * 8;
  const unsigned short* Bh = Uhi + ((size_t)(b * JCAP + (l & 15))) * KDIM + (l >> 4) * 8;
  const unsigned short* Bl = Ulo + ((size_t)(b * JCAP + (l & 15))) * KDIM + (l >> 4) * 8;
#pragma unroll
  for (int ks = 0; ks < 8; ++ks) {
    bf16x8 a = *(const bf16x8*)(Ap + ks * 32);
#pragma unroll
    for (int n = 0; n < 4; ++n) {
      bf16x8 bh = *(const bf16x8*)(Bh + (size_t)n * 16 * KDIM + ks * 32);
      acc[n] = __builtin_amdgcn_mfma_f32_16x16x32_bf16(a, bh, acc[n], 0, 0, 0);
      bf16x8 bl = *(const bf16x8*)(Bl + (size_t)n * 16 * KDIM + ks * 32);
      acc[n] = __builtin_amdgcn_mfma_f32_16x16x32_bf16(a, bl, acc[n], 0, 0, 0);
    }
  }
#pragma unroll
  for (int n = 0; n < 4; ++n)
#pragma unroll
    for (int r = 0; r < 4; ++r)
      sm.dbl[w * 16 + (l >> 4) * 4 + r][n * 16 + (l & 15)] = acc[n][r];
  __syncthreads();

  // ---- softmax over j: wave w handles local rows [w*16, w*16+16), lane = j ----
  float bold[16];
  if (pass == 1) {
    const float* src = Binit + ((size_t)(b * JCAP + l)) * ICAP + i0 + w * 16;
    for (int r = 0; r < 4; ++r) {
      f32x4 v = *(const f32x4*)(src + r * 4);
      bold[r * 4 + 0] = v.x; bold[r * 4 + 1] = v.y;
      bold[r * 4 + 2] = v.z; bold[r * 4 + 3] = v.w;
    }
  } else {
    for (int ii = 0; ii < 16; ++ii)
      bold[ii] = blog[((size_t)(b * ICAP + i0 + w * 16 + ii)) * JCAP + l];
  }
  float csl = 0.f;
  const float ubl = sm.ub[l];
  for (int ii = 0; ii < 16; ++ii) {
    float bn = bold[ii] + sm.dbl[w * 16 + ii][l] + ubl;
    if (pass == 1)
      blog[((size_t)(b * ICAP + i0 + w * 16 + ii)) * JCAP + l] = bn;
    float mx = bn;
    for (int off = 1; off < 64; off <<= 1) mx = fmaxf(mx, __shfl_xor(mx, off, 64));
    float e = __expf(bn - mx);
    float se = e;
    for (int off = 1; off < 64; off <<= 1) se += __shfl_xor(se, off, 64);
    float c = e / se;
    sm.ct[l][w * 16 + ii] = f2bf(c);
    csl += c;
  }
  sm.cpw[w][l] = csl;
  __syncthreads();

  // ---- coalesced c write + csum partial ----
  {
    const int j  = tid >> 2;
    const int ch = (tid & 3) * 16;
    unsigned pk[8];
    for (int h = 0; h < 8; ++h)
      pk[h] = *(const unsigned*)&sm.ct[j][ch + 2 * h];
    unsigned short* dst = cmat + ((size_t)(b * JCAP + j)) * ICAP + i0 + ch;
    uint4 s0; s0.x = pk[0]; s0.y = pk[1]; s0.z = pk[2]; s0.w = pk[3];
    uint4 s1; s1.x = pk[4]; s1.y = pk[5]; s1.z = pk[6]; s1.w = pk[7];
    *(uint4*)dst       = s0;
    *(uint4*)(dst + 8) = s1;
  }
  if (tid < 64)
    cpart_out[((size_t)(b * 4 + ic)) * JCAP + tid] =
        sm.cpw[0][tid] + sm.cpw[1][tid] + sm.cpw[2][tid] + sm.cpw[3][tid];
}

// ---------------------------------------------------------------------------
// k_final: v2 = squash(sum_kc spart + csum*Wb) -> out. Block per b.
// ---------------------------------------------------------------------------
__global__ __launch_bounds__(256) void k_final(
    const float* __restrict__ spart, const float* __restrict__ cpart,
    const float* __restrict__ Wb, float* __restrict__ outp)
{
  const int tid = threadIdx.x;
  const int b   = blockIdx.x;
  const float* sp = spart + (size_t)b * 4 * OUTD + tid * 8;
  f32x4 a0 = *(const f32x4*)sp;
  f32x4 a1 = *(const f32x4*)(sp + 4);
  for (int p = 1; p < 4; ++p) {
    a0 += *(const f32x4*)(sp + (size_t)p * OUTD);
    a1 += *(const f32x4*)(sp + (size_t)p * OUTD + 4);
  }
  const int j = tid >> 2;
  float cs = cpart[((size_t)b * 4) * JCAP + j] + cpart[((size_t)(b * 4 + 1)) * JCAP + j] +
             cpart[((size_t)(b * 4 + 2)) * JCAP + j] + cpart[((size_t)(b * 4 + 3)) * JCAP + j];
  f32x4 wb0 = *(const f32x4*)(Wb + tid * 8);
  f32x4 wb1 = *(const f32x4*)(Wb + tid * 8 + 4);
  float s8[8];
  s8[0] = a0.x + cs * wb0.x; s8[1] = a0.y + cs * wb0.y;
  s8[2] = a0.z + cs * wb0.z; s8[3] = a0.w + cs * wb0.w;
  s8[4] = a1.x + cs * wb1.x; s8[5] = a1.y + cs * wb1.y;
  s8[6] = a1.z + cs * wb1.z; s8[7] = a1.w + cs * wb1.w;
  float sq = 0.f;
  for (int e = 0; e < 8; ++e) sq += s8[e] * s8[e];
  sq += __shfl_xor(sq, 1, 64);
  sq += __shfl_xor(sq, 2, 64);
  float scale = (sq / (1.0f + sq)) / sqrtf(sq + 1e-8f);
  float* dst = outp + (size_t)b * OUTD + tid * 8;
  f32x4 t0 = {scale * s8[0], scale * s8[1], scale * s8[2], scale * s8[3]};
  f32x4 t1 = {scale * s8[4], scale * s8[5], scale * s8[6], scale * s8[7]};
  *(f32x4*)dst       = t0;
  *(f32x4*)(dst + 4) = t1;
}

// ---------------------------------------------------------------------------
extern "C" void kernel_launch(void* const* d_in, const int* in_sizes, int n_in,
                              void* d_out, int out_size, void* d_ws, size_t ws_size,
                              hipStream_t stream) {
  const float* x  = (const float*)d_in[0];
  const float* bi = (const float*)d_in[1];
  const float* W  = (const float*)d_in[2];
  const float* Wb = (const float*)d_in[3];
  float* out = (float*)d_out;

  char* ws = (char*)d_ws;
  const size_t MiB = 1024 * 1024;
  unsigned short* xT     = (unsigned short*)(ws + 0 * MiB);    // 8 MiB
  unsigned short* xKI    = (unsigned short*)(ws + 8 * MiB);    // 8 MiB
  unsigned short* Wbf    = (unsigned short*)(ws + 16 * MiB);   // 1 MiB
  unsigned short* cm     = (unsigned short*)(ws + 17 * MiB);   // 2 MiB
  unsigned short* Uhi    = (unsigned short*)(ws + 19 * MiB);   // 2 MiB
  unsigned short* Ulo    = (unsigned short*)(ws + 21 * MiB);   // 2 MiB
  float*          spart  = (float*)(ws + 23 * MiB);            // 2 MiB
  float*          blog   = (float*)(ws + 25 * MiB);            // 4 MiB
  float*          cpartA = (float*)(ws + 29 * MiB);            // 64 KiB
  float*          cpartB = (float*)(ws + 30 * MiB);            // 64 KiB

  prep<<<dim3(1536), 256, 0, stream>>>(W, x, bi, Wbf, xT, xKI, cm, cpartA);
  // pass 1
  k_sv<<<dim3(256), 256, 0, stream>>>(xKI, cm, Wbf, spart);
  k_u <<<dim3(256), 256, 0, stream>>>(spart, cpartA, Wb, Wbf, Uhi, Ulo);
  k_db<<<dim3(256), 256, 0, stream>>>(xT, Uhi, Ulo, spart, cpartA, Wb, bi, blog, cm, cpartB, 1);
  // pass 2
  k_sv<<<dim3(256), 256, 0, stream>>>(xKI, cm, Wbf, spart);
  k_u <<<dim3(256), 256, 0, stream>>>(spart, cpartB, Wb, Wbf, Uhi, Ulo);
  k_db<<<dim3(256), 256, 0, stream>>>(xT, Uhi, Ulo, spart, cpartB, Wb, bi, blog, cm, cpartA, 2);
  // pass 3
  k_sv<<<dim3(256), 256, 0, stream>>>(xKI, cm, Wbf, spart);
  k_final<<<dim3(64), 256, 0, stream>>>(spart, cpartA, Wb, out);
}